// Round 12
// baseline (875.151 us; speedup 1.0000x reference)
//
#include <hip/hip_runtime.h>
#include <hip/hip_bf16.h>
#include <cstdint>
#include <cstddef>

#define H_ 2880
#define E_ 8
#define FF_ 2880
#define TWO_FF 5760
#define S_ 2048
#define NPAD 5120
#define CLIPV 7.0f
#define AUXC 0.01f
#define NKS 90            // 2880 / 32

#define GRIDP  22112      // 512 router + 21600 conv_in
#define GRID1C 5120       // 160 groups x 32: 8 gemm1 + 24 conv_out
#define GRID2  640

typedef __attribute__((ext_vector_type(8))) short bf16x8;
typedef __attribute__((ext_vector_type(4))) float f32x4;

// ---------------- workspace layout (bytes) ----------------
#define WS_COUNTS   0         // int[8]
#define WS_BASEP    64        // int[9] padded bases
#define WS_NS       104       // int[2]
#define WS_SCHED_E  128       // int[1280]
#define WS_SCHED_C  5248
#define WS_SCHED_R  10368
#define WS_SCH2_E   15488     // int[640]
#define WS_SCH2_C   18048
#define WS_SCH2_R   20608
#define WS_IDX2     23168     // int[2*S]
#define WS_W2       39552     // float[2*S]
#define WS_PROBS    55936     // float[8*S]
#define WS_ENT      121472    // float[S]
#define WS_TOKL     129664    // int[5120]
#define WS_ASSW     150144    // float[5120]
#define WS_AG       262144    // bf16 slot-tiled [40][45][8][128][8]  29,491,200 B
#define WS_TIN      29753344  // bf16 tiled [8][60][45][8][96][8] 265,420,800 B
#define WS_ACT      295174144 // bf16 slot-tiled like AG           29,491,200 B
#define WS_TOUT     324665344 // bf16 tiled [8][30][45][8][96][8] 132,710,400 B

typedef const __attribute__((address_space(1))) void global_cvoid;
typedef __attribute__((address_space(3))) void lds_void;

__device__ __forceinline__ void gload_lds16(const void* g, void* l) {
  __builtin_amdgcn_global_load_lds((global_cvoid*)g, (lds_void*)l, 16, 0, 0);
}

__device__ __forceinline__ unsigned int pack2bf(float a, float b) {
  __hip_bfloat162 h = __float22bfloat162_rn(make_float2(a, b));
  union { __hip_bfloat162 h; unsigned int u; } c; c.h = h; return c.u;
}

__device__ __forceinline__ unsigned short f2bf1(float f) {
  __hip_bfloat16 h = __float2bfloat16(f);
  union { __hip_bfloat16 h; unsigned short u; } c; c.h = h; return c.u;
}

// runtime-bijective XCD chunk map (m204)
__device__ __forceinline__ int xcd_lid(int bid, int ns) {
  int q = ns >> 3, r = ns & 7;
  int xcd = bid & 7, i = bid >> 3;
  int cnt = q + (xcd < r ? 1 : 0);
  if (i >= cnt) return -1;
  return xcd * q + (xcd < r ? xcd : r) + i;
}

// ---------------- weight conversion tile body: fp32 [k][n] -> bf16 [kq][n][8] ----------------
template <int LD>
__device__ __forceinline__ void convw_body(const float* __restrict__ src,
                                           unsigned short* __restrict__ dst,
                                           float (*ls)[97]) {
  int tid = threadIdx.x;
#pragma unroll
  for (int i = 0; i < 6; ++i) {
    int u = tid + 256 * i;           // 1536 float4s = 64 rows x 24
    int r = u / 24, c4 = u % 24;
    float4 v = *(const float4*)(src + (size_t)r * LD + c4 * 4);
    ls[r][c4 * 4 + 0] = v.x; ls[r][c4 * 4 + 1] = v.y;
    ls[r][c4 * 4 + 2] = v.z; ls[r][c4 * 4 + 3] = v.w;
  }
  __syncthreads();
#pragma unroll
  for (int i = 0; i < 3; ++i) {
    int ci = tid + 256 * i;          // 768 chunks
    int kq = ci / 96, n = ci % 96;
    float f[8];
#pragma unroll
    for (int j = 0; j < 8; ++j) f[j] = ls[kq * 8 + j][n];
    uint4 o;
    o.x = pack2bf(f[0], f[1]); o.y = pack2bf(f[2], f[3]);
    o.z = pack2bf(f[4], f[5]); o.w = pack2bf(f[6], f[7]);
    *(uint4*)(dst + ci * 8) = o;
  }
}

// ---------------- k_pre: router (512, first) + conv_in (21600) ----------------
__global__ __launch_bounds__(256) void k_pre(
    const float* __restrict__ Win, unsigned short* __restrict__ Tin,
    const float* __restrict__ x, const float* __restrict__ rw,
    const float* __restrict__ rb, int* __restrict__ counts,
    int* __restrict__ idx2, float* __restrict__ wtop,
    float* __restrict__ probs, float* __restrict__ ent) {
  __shared__ float ls[64][97];
  int bid = blockIdx.x;
  if (bid >= 512) {
    int cid = bid - 512;
    int e = cid / 2700, r = cid % 2700, nt = r / 45, kb = r % 45;
    const float* src = Win + (size_t)e * H_ * TWO_FF + (size_t)kb * 64 * TWO_FF + nt * 96;
    unsigned short* dst = Tin + (((size_t)e * 60 + nt) * 45 + kb) * 6144;
    convw_body<TWO_FF>(src, dst, ls);
    return;
  }
  int wave = threadIdx.x >> 6, lane = threadIdx.x & 63;
  int s = bid * 4 + wave;
  if (s >= S_) return;
  const float* xr = x + (size_t)s * H_;
  float acc[E_];
#pragma unroll
  for (int e = 0; e < E_; ++e) acc[e] = 0.f;
  for (int k = lane; k < H_; k += 64) {
    float xv = xr[k];
#pragma unroll
    for (int e = 0; e < E_; ++e) acc[e] = fmaf(xv, rw[e * H_ + k], acc[e]);
  }
#pragma unroll
  for (int e = 0; e < E_; ++e) {
#pragma unroll
    for (int off = 32; off > 0; off >>= 1) acc[e] += __shfl_xor(acc[e], off, 64);
    acc[e] += rb[e];
  }
  if (lane == 0) {
    int i1 = 0; float v1 = acc[0];
#pragma unroll
    for (int e = 1; e < E_; ++e) if (acc[e] > v1) { v1 = acc[e]; i1 = e; }
    int i2 = -1; float v2 = -3.4e38f;
#pragma unroll
    for (int e = 0; e < E_; ++e) if (e != i1 && acc[e] > v2) { v2 = acc[e]; i2 = e; }
    float w1 = 1.f / (1.f + expf(v2 - v1));
    float w2v = 1.f - w1;
    float m = v1;
    float se = 0.f; float p[E_];
#pragma unroll
    for (int e = 0; e < E_; ++e) { p[e] = expf(acc[e] - m); se += p[e]; }
    float inv = 1.f / se; float ents = 0.f;
#pragma unroll
    for (int e = 0; e < E_; ++e) {
      p[e] *= inv;
      ents -= p[e] * logf(p[e] + 1e-10f);
      probs[(size_t)s * E_ + e] = p[e];
    }
    ent[s] = ents;
    idx2[2 * s] = i1; idx2[2 * s + 1] = i2;
    wtop[2 * s] = w1; wtop[2 * s + 1] = w2v;
    atomicAdd(&counts[i1], 1); atomicAdd(&counts[i2], 1);
  }
}

// ---------------- finalize: scalars + bases + schedules + fill + pad-fill ----------------
__global__ void k_finalize(const int* __restrict__ counts, const float* __restrict__ probs,
                           const float* __restrict__ ent, const int* __restrict__ idx2,
                           const float* __restrict__ wtop, float* __restrict__ outsc,
                           int* __restrict__ basep, int* __restrict__ sched_e,
                           int* __restrict__ sched_c, int* __restrict__ sched_r,
                           int* __restrict__ s2e, int* __restrict__ s2c,
                           int* __restrict__ s2r, int* __restrict__ nsp,
                           int* __restrict__ tokl, float* __restrict__ assw) {
  __shared__ float red[256];
  __shared__ float tot[17];
  __shared__ int sh_tc[8], sh_cum[9], sh_base[9], sfill[8];
  int t = threadIdx.x;
  float imp[8], ld[8]; float es = 0.f;
#pragma unroll
  for (int e = 0; e < 8; ++e) { imp[e] = 0.f; ld[e] = 0.f; }
  for (int s = t; s < S_; s += 256) {
#pragma unroll
    for (int e = 0; e < 8; ++e) imp[e] += probs[(size_t)s * 8 + e];
    es += ent[s];
    int e0 = idx2[2 * s], e1 = idx2[2 * s + 1];
    float a = wtop[2 * s], b = wtop[2 * s + 1];
#pragma unroll
    for (int e = 0; e < 8; ++e)
      ld[e] += (e0 == e ? a : 0.f) + (e1 == e ? b : 0.f);
  }
#pragma unroll
  for (int q = 0; q < 17; ++q) {
    float v = (q < 8) ? imp[q] : ((q < 16) ? ld[q - 8] : es);
    red[t] = v; __syncthreads();
    for (int o = 128; o > 0; o >>= 1) { if (t < o) red[t] += red[t + o]; __syncthreads(); }
    if (t == 0) tot[q] = red[0];
    __syncthreads();
  }
  if (t == 0) {
    float aux = 0.f;
#pragma unroll
    for (int e = 0; e < 8; ++e) aux += (tot[e] / (float)S_) * (tot[8 + e] / (float)S_);
    aux *= AUXC * (float)E_;
    outsc[0] = aux;
#pragma unroll
    for (int e = 0; e < 8; ++e) outsc[1 + e] = tot[8 + e] / (float)S_;
    outsc[9] = tot[16] / (float)S_;
    int bp = 0, cum = 0;
    for (int e = 0; e < 8; ++e) {
      int tc = (counts[e] + 127) >> 7;
      sh_tc[e] = tc; sh_cum[e] = cum; sh_base[e] = bp;
      basep[e] = bp;
      cum += tc; bp += tc << 7;
    }
    sh_cum[8] = cum; sh_base[8] = bp; basep[8] = bp;
    nsp[0] = cum * 30; nsp[1] = cum * 15;
  }
  if (t < 8) sfill[t] = 0;
  __syncthreads();
  int ntile = sh_cum[8];
  int ns1 = ntile * 30;
  for (int sidx = t; sidx < ns1; sidx += 256) {
    int e = 0;
    while (e < 7 && sidx >= sh_cum[e + 1] * 30) ++e;
    int tc = sh_tc[e];
    int rem = sidx - sh_cum[e] * 30;
    int col = rem / tc, tt = rem - col * tc;
    sched_e[sidx] = e; sched_c[sidx] = col; sched_r[sidx] = tt * 128;
  }
  int ns2 = ntile * 15;
  for (int sidx = t; sidx < ns2; sidx += 256) {
    int e = 0;
    while (e < 7 && sidx >= sh_cum[e + 1] * 15) ++e;
    int tc = sh_tc[e];
    int rem = sidx - sh_cum[e] * 15;
    int col = rem / tc, tt = rem - col * tc;
    s2e[sidx] = e; s2c[sidx] = col; s2r[sidx] = tt * 128;
  }
  // pad slots: token 0, weight 0 (disjoint from the fill range below)
#pragma unroll
  for (int e = 0; e < 8; ++e) {
    int st = sh_base[e] + counts[e];
    int en = sh_base[e] + (sh_tc[e] << 7);
    for (int p = st + t; p < en; p += 256) { tokl[p] = 0; assw[p] = 0.f; }
  }
  for (int s = t; s < S_; s += 256) {
#pragma unroll
    for (int k = 0; k < 2; ++k) {
      int e = idx2[2 * s + k];
      int p = sh_base[e] + atomicAdd(&sfill[e], 1);
      tokl[p] = s;
      assw[p] = wtop[2 * s + k];
    }
  }
}

// ---------------- gather x rows -> bf16 slot-tiled [tm][kb][kq][row][8] ----------------
__global__ void k_gather(const float* __restrict__ x, const int* __restrict__ tokl,
                         const int* __restrict__ basep, unsigned short* __restrict__ Ag) {
  int g = blockIdx.x;
  if (g >= basep[8]) return;
  int tok = tokl[g];
  int tm = g >> 7, r = g & 127;
  unsigned short* dst = Ag + (size_t)tm * 45 * 8192;
  const float* src = x + (size_t)tok * H_;
  for (int c = threadIdx.x; c < 360; c += 256) {
    float4 v0 = *(const float4*)(src + c * 8);
    float4 v1 = *(const float4*)(src + c * 8 + 4);
    uint4 o;
    o.x = pack2bf(v0.x, v0.y); o.y = pack2bf(v0.z, v0.w);
    o.z = pack2bf(v1.x, v1.y); o.w = pack2bf(v1.z, v1.w);
    *(uint4*)(dst + (size_t)(c >> 3) * 8192 + (c & 7) * 1024 + r * 8) = o;
  }
}

// ---------------- k_gemm1c: gemm1 (BK=32 pipeline) + conv_out, phase-interleaved ----------------
__global__ __launch_bounds__(256, 4) void k_gemm1c(
    const unsigned short* __restrict__ Ag, const unsigned short* __restrict__ Tin,
    const float* __restrict__ bin, const int* __restrict__ sched_e,
    const int* __restrict__ sched_c, const int* __restrict__ sched_r,
    const int* __restrict__ basep, const int* __restrict__ counts,
    const int* __restrict__ nsp, unsigned short* __restrict__ act,
    const float* __restrict__ Wout, unsigned short* __restrict__ Tout) {
  __shared__ __align__(16) char lds[40960];   // gemm: A[2][8K]|Bu[2][6K]|Bg[2][6K]; conv: float[64][97]
  int bid = blockIdx.x;
  int g = bid >> 5, p = bid & 31, phase = g & 3;
  if ((p & 3) != phase) {
    // ---- conv_out path: 24 of every 32 blocks, ~3 tiles each (stride 3840) ----
    int nless = (p >> 2) + (((p & 3) > phase) ? 1 : 0);
    int cid = g * 24 + (p - nless);
    float (*ls)[97] = (float(*)[97])lds;
    for (int tile = cid; tile < 10800; tile += 3840) {
      int e = tile / 1350, r2 = tile % 1350, nt = r2 / 45, kb = r2 % 45;
      const float* src = Wout + (size_t)e * FF_ * H_ + (size_t)kb * 64 * H_ + nt * 96;
      unsigned short* dst = Tout + (((size_t)e * 30 + nt) * 45 + kb) * 6144;
      convw_body<H_>(src, dst, ls);
      __syncthreads();
    }
    return;
  }
  // ---- gemm1 path ----
  int lid = g * 8 + (p >> 2);
  if (lid >= nsp[0]) return;
  int e = sched_e[lid], col = sched_c[lid], row0 = sched_r[lid];
  int n_e = counts[e], rbase = basep[e];
  int n0 = col * 96;
  int tid = threadIdx.x, lane = tid & 63, wv = tid >> 6;
  int wm = wv >> 1, wn = wv & 1;
  int tile_m = (rbase + row0) >> 7;

  const char* abase  = (const char*)Ag  + (size_t)tile_m * 45 * 16384;
  const char* bubase = (const char*)Tin + (((size_t)e * 60 + col) * 45) * 12288;
  const char* bgbase = (const char*)Tin + (((size_t)e * 60 + col + 30) * 45) * 12288;
  char* ldsA  = lds;            // 2 x 8K
  char* ldsBu = lds + 16384;    // 2 x 6K
  char* ldsBg = lds + 28672;    // 2 x 6K

// 5 loads per wave per K-step(32): 2 A + 3 B (wave-uniform)
#define ST1(BUF, KT) do {                                                        \
  int kt64_ = (KT) >> 1, h_ = (KT) & 1;                                          \
  const char* at_ = abase + (size_t)kt64_ * 16384 + h_ * 8192;                   \
  const char* bu_ = bubase + (size_t)kt64_ * 12288 + h_ * 6144;                  \
  const char* bg_ = bgbase + (size_t)kt64_ * 12288 + h_ * 6144;                  \
  gload_lds16(at_ + (wv * 2 + 0) * 1024 + lane * 16,                             \
              ldsA + (BUF) * 8192 + (wv * 2 + 0) * 1024);                        \
  gload_lds16(at_ + (wv * 2 + 1) * 1024 + lane * 16,                             \
              ldsA + (BUF) * 8192 + (wv * 2 + 1) * 1024);                        \
  if (wv < 2) {                                                                  \
    gload_lds16(bu_ + (2 * wv + 0) * 1024 + lane * 16,                           \
                ldsBu + (BUF) * 6144 + (2 * wv + 0) * 1024);                     \
    gload_lds16(bu_ + (2 * wv + 1) * 1024 + lane * 16,                           \
                ldsBu + (BUF) * 6144 + (2 * wv + 1) * 1024);                     \
    gload_lds16(bg_ + wv * 1024 + lane * 16,                                     \
                ldsBg + (BUF) * 6144 + wv * 1024);                               \
  } else {                                                                       \
    gload_lds16(bu_ + (2 + wv) * 1024 + lane * 16,                               \
                ldsBu + (BUF) * 6144 + (2 + wv) * 1024);                         \
    gload_lds16(bg_ + (2 * wv - 2) * 1024 + lane * 16,                           \
                ldsBg + (BUF) * 6144 + (2 * wv - 2) * 1024);                     \
    gload_lds16(bg_ + (2 * wv - 1) * 1024 + lane * 16,                           \
                ldsBg + (BUF) * 6144 + (2 * wv - 1) * 1024);                     \
  }                                                                              \
} while (0)

  f32x4 aU[4][3], aG[4][3];
#pragma unroll
  for (int m = 0; m < 4; ++m)
#pragma unroll
    for (int n = 0; n < 3; ++n) { aU[m][n] = (f32x4)0.f; aG[m][n] = (f32x4)0.f; }

  ST1(0, 0);
  int cur = 0;
  for (int kt = 0; kt < NKS; ++kt) {
    asm volatile("s_barrier" ::: "memory");   // B1: all waves done reading buf cur^1
    if (kt + 1 < NKS) {
      ST1(cur ^ 1, kt + 1);                   // 5 loads for next K-step
      asm volatile("s_waitcnt vmcnt(5)" ::: "memory");   // step kt landed, kt+1 in flight
    } else {
      asm volatile("s_waitcnt vmcnt(0)" ::: "memory");
    }
    asm volatile("s_barrier" ::: "memory");   // B2: step kt LDS ready everywhere
    const char* Ab  = ldsA + cur * 8192 + (lane >> 4) * 2048 + (wm * 64 + (lane & 15)) * 16;
    const char* Bub = ldsBu + cur * 6144 + (lane >> 4) * 1536 + (wn * 48 + (lane & 15)) * 16;
    const char* Bgb = ldsBg + cur * 6144 + (lane >> 4) * 1536 + (wn * 48 + (lane & 15)) * 16;
    bf16x8 af[4], bu[3], bg[3];
#pragma unroll
    for (int m = 0; m < 4; ++m) af[m] = *(const bf16x8*)(Ab + m * 256);
#pragma unroll
    for (int n = 0; n < 3; ++n) {
      bu[n] = *(const bf16x8*)(Bub + n * 256);
      bg[n] = *(const bf16x8*)(Bgb + n * 256);
    }
#pragma unroll
    for (int n = 0; n < 3; ++n)
#pragma unroll
      for (int m = 0; m < 4; ++m) {
        aU[m][n] = __builtin_amdgcn_mfma_f32_16x16x32_bf16(af[m], bu[n], aU[m][n], 0, 0, 0);
        aG[m][n] = __builtin_amdgcn_mfma_f32_16x16x32_bf16(af[m], bg[n], aG[m][n], 0, 0, 0);
      }
    cur ^= 1;
  }
#undef ST1

  float bias_u[3], bias_g[3];
#pragma unroll
  for (int n = 0; n < 3; ++n) {
    int cidx = n0 + wn * 48 + n * 16 + (lane & 15);
    bias_u[n] = bin[(size_t)e * TWO_FF + cidx];
    bias_g[n] = bin[(size_t)e * TWO_FF + FF_ + cidx];
  }
  unsigned short* atile = act + (size_t)tile_m * 45 * 8192;
#pragma unroll
  for (int m = 0; m < 4; ++m) {
#pragma unroll
    for (int q = 0; q < 4; ++q) {
      int r = wm * 64 + m * 16 + (lane >> 4) * 4 + q;
      if (row0 + r < n_e) {
#pragma unroll
        for (int n = 0; n < 3; ++n) {
          int cidx = n0 + wn * 48 + n * 16 + (lane & 15);
          float u = aU[m][n][q] + bias_u[n];
          float gg = aG[m][n][q] + bias_g[n];
          u = fminf(fmaxf(u, -CLIPV), CLIPV);
          gg = fminf(fmaxf(gg, -CLIPV), CLIPV);
          float sig = 1.f / (1.f + expf(-gg));
          atile[(size_t)(cidx >> 6) * 8192 + ((cidx >> 3) & 7) * 1024 + r * 8 + (cidx & 7)]
              = f2bf1(gg * sig * u);
        }
      }
    }
  }
}

// ---------------- GEMM2 (BK=32 pipeline): act x Tout -> out ----------------
__global__ __launch_bounds__(256, 4) void k_gemm2(
    const unsigned short* __restrict__ act, const unsigned short* __restrict__ Tout,
    const float* __restrict__ bout, const int* __restrict__ s2e,
    const int* __restrict__ s2c, const int* __restrict__ s2r,
    const int* __restrict__ basep, const int* __restrict__ counts,
    const int* __restrict__ nsp, const int* __restrict__ tokl,
    const float* __restrict__ assw, float* __restrict__ out) {
  __shared__ __align__(16) char lds[40960];   // A[2][8K] | B[2][12K]
  int lid = xcd_lid(blockIdx.x, nsp[1]);
  if (lid < 0) return;
  int e = s2e[lid], col = s2c[lid], row0 = s2r[lid];
  int n_e = counts[e], rbase = basep[e];
  int n0 = col * 192;
  int tid = threadIdx.x, lane = tid & 63, wv = tid >> 6;
  int wm = wv >> 1, wn = wv & 1;
  int tile_m = (rbase + row0) >> 7;

  const char* abase = (const char*)act + (size_t)tile_m * 45 * 16384;
  const char* bbase = (const char*)Tout + (((size_t)e * 30 + col * 2) * 45) * 12288;
  char* ldsA = lds;            // 2 x 8K
  char* ldsB = lds + 16384;    // 2 x 12K

// 5 loads per wave per K-step(32): 2 A + 3 B
#define ST2(BUF, KT) do {                                                        \
  int kt64_ = (KT) >> 1, h_ = (KT) & 1;                                          \
  const char* at_ = abase + (size_t)kt64_ * 16384 + h_ * 8192;                   \
  gload_lds16(at_ + (wv * 2 + 0) * 1024 + lane * 16,                             \
              ldsA + (BUF) * 8192 + (wv * 2 + 0) * 1024);                        \
  gload_lds16(at_ + (wv * 2 + 1) * 1024 + lane * 16,                             \
              ldsA + (BUF) * 8192 + (wv * 2 + 1) * 1024);                        \
  _Pragma("unroll") for (int i_ = 0; i_ < 3; ++i_) {                             \
    int ch_ = wv * 3 + i_;                                                       \
    const char* bt_ = bbase + (size_t)(ch_ / 6) * 45 * 12288                     \
                      + (size_t)kt64_ * 12288 + h_ * 6144 + (ch_ % 6) * 1024;    \
    gload_lds16(bt_ + lane * 16, ldsB + (BUF) * 12288 + ch_ * 1024); }           \
} while (0)

  f32x4 acc[4][6];
#pragma unroll
  for (int m = 0; m < 4; ++m)
#pragma unroll
    for (int n = 0; n < 6; ++n) acc[m][n] = (f32x4)0.f;

  ST2(0, 0);
  int cur = 0;
  for (int kt = 0; kt < NKS; ++kt) {
    asm volatile("s_barrier" ::: "memory");   // B1
    if (kt + 1 < NKS) {
      ST2(cur ^ 1, kt + 1);                   // 5 loads for next K-step
      asm volatile("s_waitcnt vmcnt(5)" ::: "memory");
    } else {
      asm volatile("s_waitcnt vmcnt(0)" ::: "memory");
    }
    asm volatile("s_barrier" ::: "memory");   // B2
    const char* Ab = ldsA + cur * 8192 + (lane >> 4) * 2048 + (wm * 64 + (lane & 15)) * 16;
    const char* Bb = ldsB + cur * 12288 + wn * 6144 + (lane >> 4) * 1536 + (lane & 15) * 16;
    bf16x8 af[4], bf[6];
#pragma unroll
    for (int m = 0; m < 4; ++m) af[m] = *(const bf16x8*)(Ab + m * 256);
#pragma unroll
    for (int n = 0; n < 6; ++n) bf[n] = *(const bf16x8*)(Bb + n * 256);
#pragma unroll
    for (int n = 0; n < 6; ++n)
#pragma unroll
      for (int m = 0; m < 4; ++m)
        acc[m][n] = __builtin_amdgcn_mfma_f32_16x16x32_bf16(af[m], bf[n], acc[m][n], 0, 0, 0);
    cur ^= 1;
  }
#undef ST2

  float bb[6];
#pragma unroll
  for (int n = 0; n < 6; ++n)
    bb[n] = bout[(size_t)e * H_ + n0 + wn * 96 + n * 16 + (lane & 15)];
#pragma unroll
  for (int m = 0; m < 4; ++m) {
#pragma unroll
    for (int q = 0; q < 4; ++q) {
      int r = wm * 64 + m * 16 + (lane >> 4) * 4 + q;
      if (row0 + r < n_e) {
        int g = rbase + row0 + r;
        int tok = tokl[g];
        float w = assw[g];
        float* orow = out + (size_t)tok * H_;
#pragma unroll
        for (int n = 0; n < 6; ++n) {
          int cidx = n0 + wn * 96 + n * 16 + (lane & 15);
          atomicAdd(&orow[cidx], w * (acc[m][n][q] + bb[n]));
        }
      }
    }
  }
}

// ---------------- launch ----------------
extern "C" void kernel_launch(void* const* d_in, const int* in_sizes, int n_in,
                              void* d_out, int out_size, void* d_ws, size_t ws_size,
                              hipStream_t stream) {
  (void)in_sizes; (void)n_in; (void)ws_size;
  const float* x        = (const float*)d_in[0];
  const float* W_in     = (const float*)d_in[1];
  const float* b_in     = (const float*)d_in[2];
  const float* W_out    = (const float*)d_in[3];
  const float* b_out    = (const float*)d_in[4];
  const float* router_w = (const float*)d_in[5];
  const float* router_b = (const float*)d_in[6];
  float* out = (float*)d_out;
  char* ws = (char*)d_ws;

  int*   counts  = (int*)(ws + WS_COUNTS);
  int*   basep   = (int*)(ws + WS_BASEP);
  int*   nsp     = (int*)(ws + WS_NS);
  int*   sched_e = (int*)(ws + WS_SCHED_E);
  int*   sched_c = (int*)(ws + WS_SCHED_C);
  int*   sched_r = (int*)(ws + WS_SCHED_R);
  int*   s2e     = (int*)(ws + WS_SCH2_E);
  int*   s2c     = (int*)(ws + WS_SCH2_C);
  int*   s2r     = (int*)(ws + WS_SCH2_R);
  int*   idx2    = (int*)(ws + WS_IDX2);
  float* wtop    = (float*)(ws + WS_W2);
  float* probs   = (float*)(ws + WS_PROBS);
  float* ent     = (float*)(ws + WS_ENT);
  int*   tokl    = (int*)(ws + WS_TOKL);
  float* assw    = (float*)(ws + WS_ASSW);
  unsigned short* Ag   = (unsigned short*)(ws + WS_AG);
  unsigned short* Tin  = (unsigned short*)(ws + WS_TIN);
  unsigned short* actp = (unsigned short*)(ws + WS_ACT);
  unsigned short* Tout = (unsigned short*)(ws + WS_TOUT);

  hipMemsetAsync(ws, 0, 128, stream);   // counts only; pads filled by finalize
  hipMemsetAsync(d_out, 0, (size_t)out_size * sizeof(float), stream);

  k_pre<<<GRIDP, 256, 0, stream>>>(W_in, Tin, x, router_w, router_b,
                                   counts, idx2, wtop, probs, ent);
  k_finalize<<<1, 256, 0, stream>>>(counts, probs, ent, idx2, wtop,
                                    out + (size_t)S_ * H_, basep,
                                    sched_e, sched_c, sched_r,
                                    s2e, s2c, s2r, nsp, tokl, assw);
  k_gather<<<NPAD, 256, 0, stream>>>(x, tokl, basep, Ag);
  k_gemm1c<<<GRID1C, 256, 0, stream>>>(Ag, Tin, b_in, sched_e, sched_c, sched_r,
                                       basep, counts, nsp, actp, W_out, Tout);
  k_gemm2<<<GRID2, 256, 0, stream>>>(actp, Tout, b_out, s2e, s2c, s2r,
                                     basep, counts, nsp, tokl, assw, out);
}

// Round 13
// 608.029 us; speedup vs baseline: 1.4393x; 1.4393x over previous
//
#include <hip/hip_runtime.h>
#include <hip/hip_bf16.h>
#include <cstdint>
#include <cstddef>

#define H_ 2880
#define E_ 8
#define FF_ 2880
#define TWO_FF 5760
#define S_ 2048
#define NPAD 5120
#define CLIPV 7.0f
#define AUXC 0.01f
#define NKB 45            // 2880 / 64

#define GRIDP  22112      // 512 router + 21600 conv_in
#define GRID1C 5120       // 160 groups x 32: 8 gemm1 + 24 conv_out
#define GRID2  640

typedef __attribute__((ext_vector_type(8))) short bf16x8;
typedef __attribute__((ext_vector_type(4))) float f32x4;

// ---------------- workspace layout (bytes) ----------------
#define WS_COUNTS   0         // int[8]
#define WS_BASEP    64        // int[9] padded bases
#define WS_NS       104       // int[2]
#define WS_SCHED_E  128       // int[1280]
#define WS_SCHED_C  5248
#define WS_SCHED_R  10368
#define WS_SCH2_E   15488     // int[640]
#define WS_SCH2_C   18048
#define WS_SCH2_R   20608
#define WS_IDX2     23168     // int[2*S]
#define WS_W2       39552     // float[2*S]
#define WS_PROBS    55936     // float[8*S]
#define WS_ENT      121472    // float[S]
#define WS_TOKL     129664    // int[5120]
#define WS_ASSW     150144    // float[5120]
#define WS_AG       262144    // bf16 slot-tiled [40][45][8][128][8]  29,491,200 B
#define WS_TIN      29753344  // bf16 tiled [8][60][45][8][96][8] 265,420,800 B
#define WS_ACT      295174144 // bf16 slot-tiled like AG           29,491,200 B
#define WS_TOUT     324665344 // bf16 tiled [8][30][45][8][96][8] 132,710,400 B

typedef const __attribute__((address_space(1))) void global_cvoid;
typedef __attribute__((address_space(3))) void lds_void;

__device__ __forceinline__ void gload_lds16(const void* g, void* l) {
  __builtin_amdgcn_global_load_lds((global_cvoid*)g, (lds_void*)l, 16, 0, 0);
}

__device__ __forceinline__ unsigned int pack2bf(float a, float b) {
  __hip_bfloat162 h = __float22bfloat162_rn(make_float2(a, b));
  union { __hip_bfloat162 h; unsigned int u; } c; c.h = h; return c.u;
}

__device__ __forceinline__ unsigned short f2bf1(float f) {
  __hip_bfloat16 h = __float2bfloat16(f);
  union { __hip_bfloat16 h; unsigned short u; } c; c.h = h; return c.u;
}

// runtime-bijective XCD chunk map (m204)
__device__ __forceinline__ int xcd_lid(int bid, int ns) {
  int q = ns >> 3, r = ns & 7;
  int xcd = bid & 7, i = bid >> 3;
  int cnt = q + (xcd < r ? 1 : 0);
  if (i >= cnt) return -1;
  return xcd * q + (xcd < r ? xcd : r) + i;
}

// ---------------- weight conversion tile body: fp32 [k][n] -> bf16 [kq][n][8] ----------------
template <int LD>
__device__ __forceinline__ void convw_body(const float* __restrict__ src,
                                           unsigned short* __restrict__ dst,
                                           float (*ls)[97]) {
  int tid = threadIdx.x;
#pragma unroll
  for (int i = 0; i < 6; ++i) {
    int u = tid + 256 * i;           // 1536 float4s = 64 rows x 24
    int r = u / 24, c4 = u % 24;
    float4 v = *(const float4*)(src + (size_t)r * LD + c4 * 4);
    ls[r][c4 * 4 + 0] = v.x; ls[r][c4 * 4 + 1] = v.y;
    ls[r][c4 * 4 + 2] = v.z; ls[r][c4 * 4 + 3] = v.w;
  }
  __syncthreads();
#pragma unroll
  for (int i = 0; i < 3; ++i) {
    int ci = tid + 256 * i;          // 768 chunks
    int kq = ci / 96, n = ci % 96;
    float f[8];
#pragma unroll
    for (int j = 0; j < 8; ++j) f[j] = ls[kq * 8 + j][n];
    uint4 o;
    o.x = pack2bf(f[0], f[1]); o.y = pack2bf(f[2], f[3]);
    o.z = pack2bf(f[4], f[5]); o.w = pack2bf(f[6], f[7]);
    *(uint4*)(dst + ci * 8) = o;
  }
}

// ---------------- k_pre: router (512, first) + conv_in (21600) ----------------
__global__ __launch_bounds__(256) void k_pre(
    const float* __restrict__ Win, unsigned short* __restrict__ Tin,
    const float* __restrict__ x, const float* __restrict__ rw,
    const float* __restrict__ rb, int* __restrict__ counts,
    int* __restrict__ idx2, float* __restrict__ wtop,
    float* __restrict__ probs, float* __restrict__ ent) {
  __shared__ float ls[64][97];
  int bid = blockIdx.x;
  if (bid >= 512) {
    int cid = bid - 512;
    int e = cid / 2700, r = cid % 2700, nt = r / 45, kb = r % 45;
    const float* src = Win + (size_t)e * H_ * TWO_FF + (size_t)kb * 64 * TWO_FF + nt * 96;
    unsigned short* dst = Tin + (((size_t)e * 60 + nt) * 45 + kb) * 6144;
    convw_body<TWO_FF>(src, dst, ls);
    return;
  }
  int wave = threadIdx.x >> 6, lane = threadIdx.x & 63;
  int s = bid * 4 + wave;
  if (s >= S_) return;
  const float* xr = x + (size_t)s * H_;
  float acc[E_];
#pragma unroll
  for (int e = 0; e < E_; ++e) acc[e] = 0.f;
  for (int k = lane; k < H_; k += 64) {
    float xv = xr[k];
#pragma unroll
    for (int e = 0; e < E_; ++e) acc[e] = fmaf(xv, rw[e * H_ + k], acc[e]);
  }
#pragma unroll
  for (int e = 0; e < E_; ++e) {
#pragma unroll
    for (int off = 32; off > 0; off >>= 1) acc[e] += __shfl_xor(acc[e], off, 64);
    acc[e] += rb[e];
  }
  if (lane == 0) {
    int i1 = 0; float v1 = acc[0];
#pragma unroll
    for (int e = 1; e < E_; ++e) if (acc[e] > v1) { v1 = acc[e]; i1 = e; }
    int i2 = -1; float v2 = -3.4e38f;
#pragma unroll
    for (int e = 0; e < E_; ++e) if (e != i1 && acc[e] > v2) { v2 = acc[e]; i2 = e; }
    float w1 = 1.f / (1.f + expf(v2 - v1));
    float w2v = 1.f - w1;
    float m = v1;
    float se = 0.f; float p[E_];
#pragma unroll
    for (int e = 0; e < E_; ++e) { p[e] = expf(acc[e] - m); se += p[e]; }
    float inv = 1.f / se; float ents = 0.f;
#pragma unroll
    for (int e = 0; e < E_; ++e) {
      p[e] *= inv;
      ents -= p[e] * logf(p[e] + 1e-10f);
      probs[(size_t)s * E_ + e] = p[e];
    }
    ent[s] = ents;
    idx2[2 * s] = i1; idx2[2 * s + 1] = i2;
    wtop[2 * s] = w1; wtop[2 * s + 1] = w2v;
    atomicAdd(&counts[i1], 1); atomicAdd(&counts[i2], 1);
  }
}

// ---------------- finalize: scalars + bases + schedules + fill + pad-fill ----------------
__global__ void k_finalize(const int* __restrict__ counts, const float* __restrict__ probs,
                           const float* __restrict__ ent, const int* __restrict__ idx2,
                           const float* __restrict__ wtop, float* __restrict__ outsc,
                           int* __restrict__ basep, int* __restrict__ sched_e,
                           int* __restrict__ sched_c, int* __restrict__ sched_r,
                           int* __restrict__ s2e, int* __restrict__ s2c,
                           int* __restrict__ s2r, int* __restrict__ nsp,
                           int* __restrict__ tokl, float* __restrict__ assw) {
  __shared__ float red[256];
  __shared__ float tot[17];
  __shared__ int sh_tc[8], sh_cum[9], sh_base[9], sfill[8];
  int t = threadIdx.x;
  float imp[8], ld[8]; float es = 0.f;
#pragma unroll
  for (int e = 0; e < 8; ++e) { imp[e] = 0.f; ld[e] = 0.f; }
  for (int s = t; s < S_; s += 256) {
#pragma unroll
    for (int e = 0; e < 8; ++e) imp[e] += probs[(size_t)s * 8 + e];
    es += ent[s];
    int e0 = idx2[2 * s], e1 = idx2[2 * s + 1];
    float a = wtop[2 * s], b = wtop[2 * s + 1];
#pragma unroll
    for (int e = 0; e < 8; ++e)
      ld[e] += (e0 == e ? a : 0.f) + (e1 == e ? b : 0.f);
  }
#pragma unroll
  for (int q = 0; q < 17; ++q) {
    float v = (q < 8) ? imp[q] : ((q < 16) ? ld[q - 8] : es);
    red[t] = v; __syncthreads();
    for (int o = 128; o > 0; o >>= 1) { if (t < o) red[t] += red[t + o]; __syncthreads(); }
    if (t == 0) tot[q] = red[0];
    __syncthreads();
  }
  if (t == 0) {
    float aux = 0.f;
#pragma unroll
    for (int e = 0; e < 8; ++e) aux += (tot[e] / (float)S_) * (tot[8 + e] / (float)S_);
    aux *= AUXC * (float)E_;
    outsc[0] = aux;
#pragma unroll
    for (int e = 0; e < 8; ++e) outsc[1 + e] = tot[8 + e] / (float)S_;
    outsc[9] = tot[16] / (float)S_;
    int bp = 0, cum = 0;
    for (int e = 0; e < 8; ++e) {
      int tc = (counts[e] + 127) >> 7;
      sh_tc[e] = tc; sh_cum[e] = cum; sh_base[e] = bp;
      basep[e] = bp;
      cum += tc; bp += tc << 7;
    }
    sh_cum[8] = cum; sh_base[8] = bp; basep[8] = bp;
    nsp[0] = cum * 30; nsp[1] = cum * 15;
  }
  if (t < 8) sfill[t] = 0;
  __syncthreads();
  int ntile = sh_cum[8];
  int ns1 = ntile * 30;
  for (int sidx = t; sidx < ns1; sidx += 256) {
    int e = 0;
    while (e < 7 && sidx >= sh_cum[e + 1] * 30) ++e;
    int tc = sh_tc[e];
    int rem = sidx - sh_cum[e] * 30;
    int col = rem / tc, tt = rem - col * tc;
    sched_e[sidx] = e; sched_c[sidx] = col; sched_r[sidx] = tt * 128;
  }
  int ns2 = ntile * 15;
  for (int sidx = t; sidx < ns2; sidx += 256) {
    int e = 0;
    while (e < 7 && sidx >= sh_cum[e + 1] * 15) ++e;
    int tc = sh_tc[e];
    int rem = sidx - sh_cum[e] * 15;
    int col = rem / tc, tt = rem - col * tc;
    s2e[sidx] = e; s2c[sidx] = col; s2r[sidx] = tt * 128;
  }
  // pad slots: token 0, weight 0 (disjoint from the fill range below)
#pragma unroll
  for (int e = 0; e < 8; ++e) {
    int st = sh_base[e] + counts[e];
    int en = sh_base[e] + (sh_tc[e] << 7);
    for (int p = st + t; p < en; p += 256) { tokl[p] = 0; assw[p] = 0.f; }
  }
  for (int s = t; s < S_; s += 256) {
#pragma unroll
    for (int k = 0; k < 2; ++k) {
      int e = idx2[2 * s + k];
      int p = sh_base[e] + atomicAdd(&sfill[e], 1);
      tokl[p] = s;
      assw[p] = wtop[2 * s + k];
    }
  }
}

// ---------------- gather x rows -> bf16 slot-tiled [tm][kb][kq][row][8] ----------------
__global__ void k_gather(const float* __restrict__ x, const int* __restrict__ tokl,
                         const int* __restrict__ basep, unsigned short* __restrict__ Ag) {
  int g = blockIdx.x;
  if (g >= basep[8]) return;
  int tok = tokl[g];
  int tm = g >> 7, r = g & 127;
  unsigned short* dst = Ag + (size_t)tm * 45 * 8192;
  const float* src = x + (size_t)tok * H_;
  for (int c = threadIdx.x; c < 360; c += 256) {
    float4 v0 = *(const float4*)(src + c * 8);
    float4 v1 = *(const float4*)(src + c * 8 + 4);
    uint4 o;
    o.x = pack2bf(v0.x, v0.y); o.y = pack2bf(v0.z, v0.w);
    o.z = pack2bf(v1.x, v1.y); o.w = pack2bf(v1.z, v1.w);
    *(uint4*)(dst + (size_t)(c >> 3) * 8192 + (c & 7) * 1024 + r * 8) = o;
  }
}

// ---------------- k_gemm1c: gemm1 (phase-interleaved) + conv_out ----------------
__global__ __launch_bounds__(256, 2) void k_gemm1c(
    const unsigned short* __restrict__ Ag, const unsigned short* __restrict__ Tin,
    const float* __restrict__ bin, const int* __restrict__ sched_e,
    const int* __restrict__ sched_c, const int* __restrict__ sched_r,
    const int* __restrict__ basep, const int* __restrict__ counts,
    const int* __restrict__ nsp, unsigned short* __restrict__ act,
    const float* __restrict__ Wout, unsigned short* __restrict__ Tout) {
  __shared__ __align__(16) char lds[81920];   // gemm: A[2][16K]|Bu[2][12K]|Bg[2][12K]; conv: float[64][97]
  int bid = blockIdx.x;
  int g = bid >> 5, p = bid & 31, phase = g & 3;
  if ((p & 3) != phase) {
    // ---- conv_out path: 24 of every 32 blocks, 3 tiles each (stride 3840) ----
    int nless = (p >> 2) + (((p & 3) > phase) ? 1 : 0);
    int cid = g * 24 + (p - nless);
    float (*ls)[97] = (float(*)[97])lds;
    for (int tile = cid; tile < 10800; tile += 3840) {
      int e = tile / 1350, r2 = tile % 1350, nt = r2 / 45, kb = r2 % 45;
      const float* src = Wout + (size_t)e * FF_ * H_ + (size_t)kb * 64 * H_ + nt * 96;
      unsigned short* dst = Tout + (((size_t)e * 30 + nt) * 45 + kb) * 6144;
      convw_body<H_>(src, dst, ls);
      __syncthreads();
    }
    return;
  }
  // ---- gemm1 path ----
  int lid = g * 8 + (p >> 2);
  if (lid >= nsp[0]) return;
  int e = sched_e[lid], col = sched_c[lid], row0 = sched_r[lid];
  int n_e = counts[e], rbase = basep[e];
  int n0 = col * 96;
  int tid = threadIdx.x, lane = tid & 63, wv = tid >> 6;
  int wm = wv >> 1, wn = wv & 1;
  int tile_m = (rbase + row0) >> 7;

  const char* abase  = (const char*)Ag  + (size_t)tile_m * 45 * 16384;
  const char* bubase = (const char*)Tin + (((size_t)e * 60 + col) * 45) * 12288;
  const char* bgbase = (const char*)Tin + (((size_t)e * 60 + col + 30) * 45) * 12288;

#define ST1(BUF, KT) do {                                                        \
  const char* at_ = abase + (size_t)(KT) * 16384;                                \
  const char* bu_ = bubase + (size_t)(KT) * 12288;                               \
  const char* bg_ = bgbase + (size_t)(KT) * 12288;                               \
  _Pragma("unroll") for (int i_ = 0; i_ < 4; ++i_)                               \
    gload_lds16(at_ + (wv * 4 + i_) * 1024 + lane * 16,                          \
                lds + (BUF) * 16384 + (wv * 4 + i_) * 1024);                     \
  _Pragma("unroll") for (int i_ = 0; i_ < 3; ++i_) {                             \
    gload_lds16(bu_ + (wv * 3 + i_) * 1024 + lane * 16,                          \
                lds + 32768 + (BUF) * 12288 + (wv * 3 + i_) * 1024);             \
    gload_lds16(bg_ + (wv * 3 + i_) * 1024 + lane * 16,                          \
                lds + 57344 + (BUF) * 12288 + (wv * 3 + i_) * 1024); }           \
} while (0)

  f32x4 aU[4][3], aG[4][3];
#pragma unroll
  for (int m = 0; m < 4; ++m)
#pragma unroll
    for (int n = 0; n < 3; ++n) { aU[m][n] = (f32x4)0.f; aG[m][n] = (f32x4)0.f; }

  ST1(0, 0);
  int cur = 0;
  for (int kt = 0; kt < NKB; ++kt) {
    asm volatile("s_barrier" ::: "memory");   // B1: all waves done reading buf cur^1
    if (kt + 1 < NKB) {
      ST1(cur ^ 1, kt + 1);                   // 10 loads for next tile
      asm volatile("s_waitcnt vmcnt(10)" ::: "memory");   // tile kt landed, t+1 in flight
    } else {
      asm volatile("s_waitcnt vmcnt(0)" ::: "memory");
    }
    asm volatile("s_barrier" ::: "memory");   // B2: tile kt LDS ready everywhere
    const char* Ab  = lds + cur * 16384 + (lane >> 4) * 2048 + (wm * 64 + (lane & 15)) * 16;
    const char* Bub = lds + 32768 + cur * 12288 + (lane >> 4) * 1536 + (wn * 48 + (lane & 15)) * 16;
    const char* Bgb = Bub + 24576;
#pragma unroll
    for (int s = 0; s < 2; ++s) {
      bf16x8 af[4], bu[3], bg[3];
#pragma unroll
      for (int m = 0; m < 4; ++m) af[m] = *(const bf16x8*)(Ab + s * 8192 + m * 256);
#pragma unroll
      for (int n = 0; n < 3; ++n) {
        bu[n] = *(const bf16x8*)(Bub + s * 6144 + n * 256);
        bg[n] = *(const bf16x8*)(Bgb + s * 6144 + n * 256);
      }
#pragma unroll
      for (int n = 0; n < 3; ++n)
#pragma unroll
        for (int m = 0; m < 4; ++m) {
          aU[m][n] = __builtin_amdgcn_mfma_f32_16x16x32_bf16(af[m], bu[n], aU[m][n], 0, 0, 0);
          aG[m][n] = __builtin_amdgcn_mfma_f32_16x16x32_bf16(af[m], bg[n], aG[m][n], 0, 0, 0);
        }
    }
    cur ^= 1;
  }
#undef ST1

  float bias_u[3], bias_g[3];
#pragma unroll
  for (int n = 0; n < 3; ++n) {
    int cidx = n0 + wn * 48 + n * 16 + (lane & 15);
    bias_u[n] = bin[(size_t)e * TWO_FF + cidx];
    bias_g[n] = bin[(size_t)e * TWO_FF + FF_ + cidx];
  }
  unsigned short* atile = act + (size_t)tile_m * 45 * 8192;
#pragma unroll
  for (int m = 0; m < 4; ++m) {
#pragma unroll
    for (int q = 0; q < 4; ++q) {
      int r = wm * 64 + m * 16 + (lane >> 4) * 4 + q;
      if (row0 + r < n_e) {
#pragma unroll
        for (int n = 0; n < 3; ++n) {
          int cidx = n0 + wn * 48 + n * 16 + (lane & 15);
          float u = aU[m][n][q] + bias_u[n];
          float gg = aG[m][n][q] + bias_g[n];
          u = fminf(fmaxf(u, -CLIPV), CLIPV);
          gg = fminf(fmaxf(gg, -CLIPV), CLIPV);
          float sig = 1.f / (1.f + expf(-gg));
          atile[(size_t)(cidx >> 6) * 8192 + ((cidx >> 3) & 7) * 1024 + r * 8 + (cidx & 7)]
              = f2bf1(gg * sig * u);
        }
      }
    }
  }
}

// ---------------- GEMM2: act x Tout -> out (scatter-add weighted) ----------------
__global__ __launch_bounds__(256, 2) void k_gemm2(
    const unsigned short* __restrict__ act, const unsigned short* __restrict__ Tout,
    const float* __restrict__ bout, const int* __restrict__ s2e,
    const int* __restrict__ s2c, const int* __restrict__ s2r,
    const int* __restrict__ basep, const int* __restrict__ counts,
    const int* __restrict__ nsp, const int* __restrict__ tokl,
    const float* __restrict__ assw, float* __restrict__ out) {
  __shared__ __align__(16) char lds[81920];   // A[2][16K] | B[2][24K]
  int lid = xcd_lid(blockIdx.x, nsp[1]);
  if (lid < 0) return;
  int e = s2e[lid], col = s2c[lid], row0 = s2r[lid];
  int n_e = counts[e], rbase = basep[e];
  int n0 = col * 192;
  int tid = threadIdx.x, lane = tid & 63, wv = tid >> 6;
  int wm = wv >> 1, wn = wv & 1;
  int tile_m = (rbase + row0) >> 7;

  const char* abase = (const char*)act + (size_t)tile_m * 45 * 16384;
  const char* bbase = (const char*)Tout + (((size_t)e * 30 + col * 2) * 45) * 12288;

#define ST2(BUF, KT) do {                                                        \
  const char* at_ = abase + (size_t)(KT) * 16384;                                \
  _Pragma("unroll") for (int i_ = 0; i_ < 4; ++i_)                               \
    gload_lds16(at_ + (wv * 4 + i_) * 1024 + lane * 16,                          \
                lds + (BUF) * 16384 + (wv * 4 + i_) * 1024);                     \
  _Pragma("unroll") for (int i_ = 0; i_ < 6; ++i_) {                             \
    int ch_ = wv * 6 + i_;                                                       \
    const char* bt_ = bbase + (size_t)(ch_ / 12) * 45 * 12288                    \
                      + (size_t)(KT) * 12288 + (ch_ % 12) * 1024;                \
    gload_lds16(bt_ + lane * 16, lds + 32768 + (BUF) * 24576 + ch_ * 1024); }    \
} while (0)

  f32x4 acc[4][6];
#pragma unroll
  for (int m = 0; m < 4; ++m)
#pragma unroll
    for (int n = 0; n < 6; ++n) acc[m][n] = (f32x4)0.f;

  ST2(0, 0);
  int cur = 0;
  for (int kt = 0; kt < NKB; ++kt) {
    asm volatile("s_barrier" ::: "memory");   // B1
    if (kt + 1 < NKB) {
      ST2(cur ^ 1, kt + 1);                   // 10 loads for next tile
      asm volatile("s_waitcnt vmcnt(10)" ::: "memory");
    } else {
      asm volatile("s_waitcnt vmcnt(0)" ::: "memory");
    }
    asm volatile("s_barrier" ::: "memory");   // B2
    const char* Ab = lds + cur * 16384 + (lane >> 4) * 2048 + (wm * 64 + (lane & 15)) * 16;
    const char* Bb = lds + 32768 + cur * 24576 + wn * 12288 + (lane >> 4) * 1536 + (lane & 15) * 16;
#pragma unroll
    for (int s = 0; s < 2; ++s) {
      bf16x8 af[4], bf[6];
#pragma unroll
      for (int m = 0; m < 4; ++m) af[m] = *(const bf16x8*)(Ab + s * 8192 + m * 256);
#pragma unroll
      for (int n = 0; n < 6; ++n) bf[n] = *(const bf16x8*)(Bb + s * 6144 + n * 256);
#pragma unroll
      for (int n = 0; n < 6; ++n)
#pragma unroll
        for (int m = 0; m < 4; ++m)
          acc[m][n] = __builtin_amdgcn_mfma_f32_16x16x32_bf16(af[m], bf[n], acc[m][n], 0, 0, 0);
    }
    cur ^= 1;
  }
#undef ST2

  float bb[6];
#pragma unroll
  for (int n = 0; n < 6; ++n)
    bb[n] = bout[(size_t)e * H_ + n0 + wn * 96 + n * 16 + (lane & 15)];
#pragma unroll
  for (int m = 0; m < 4; ++m) {
#pragma unroll
    for (int q = 0; q < 4; ++q) {
      int r = wm * 64 + m * 16 + (lane >> 4) * 4 + q;
      if (row0 + r < n_e) {
        int g = rbase + row0 + r;
        int tok = tokl[g];
        float w = assw[g];
        float* orow = out + (size_t)tok * H_;
#pragma unroll
        for (int n = 0; n < 6; ++n) {
          int cidx = n0 + wn * 96 + n * 16 + (lane & 15);
          atomicAdd(&orow[cidx], w * (acc[m][n][q] + bb[n]));
        }
      }
    }
  }
}

// ---------------- launch ----------------
extern "C" void kernel_launch(void* const* d_in, const int* in_sizes, int n_in,
                              void* d_out, int out_size, void* d_ws, size_t ws_size,
                              hipStream_t stream) {
  (void)in_sizes; (void)n_in; (void)ws_size;
  const float* x        = (const float*)d_in[0];
  const float* W_in     = (const float*)d_in[1];
  const float* b_in     = (const float*)d_in[2];
  const float* W_out    = (const float*)d_in[3];
  const float* b_out    = (const float*)d_in[4];
  const float* router_w = (const float*)d_in[5];
  const float* router_b = (const float*)d_in[6];
  float* out = (float*)d_out;
  char* ws = (char*)d_ws;

  int*   counts  = (int*)(ws + WS_COUNTS);
  int*   basep   = (int*)(ws + WS_BASEP);
  int*   nsp     = (int*)(ws + WS_NS);
  int*   sched_e = (int*)(ws + WS_SCHED_E);
  int*   sched_c = (int*)(ws + WS_SCHED_C);
  int*   sched_r = (int*)(ws + WS_SCHED_R);
  int*   s2e     = (int*)(ws + WS_SCH2_E);
  int*   s2c     = (int*)(ws + WS_SCH2_C);
  int*   s2r     = (int*)(ws + WS_SCH2_R);
  int*   idx2    = (int*)(ws + WS_IDX2);
  float* wtop    = (float*)(ws + WS_W2);
  float* probs   = (float*)(ws + WS_PROBS);
  float* ent     = (float*)(ws + WS_ENT);
  int*   tokl    = (int*)(ws + WS_TOKL);
  float* assw    = (float*)(ws + WS_ASSW);
  unsigned short* Ag   = (unsigned short*)(ws + WS_AG);
  unsigned short* Tin  = (unsigned short*)(ws + WS_TIN);
  unsigned short* actp = (unsigned short*)(ws + WS_ACT);
  unsigned short* Tout = (unsigned short*)(ws + WS_TOUT);

  hipMemsetAsync(ws, 0, 128, stream);   // counts only; pads filled by finalize
  hipMemsetAsync(d_out, 0, (size_t)out_size * sizeof(float), stream);

  k_pre<<<GRIDP, 256, 0, stream>>>(W_in, Tin, x, router_w, router_b,
                                   counts, idx2, wtop, probs, ent);
  k_finalize<<<1, 256, 0, stream>>>(counts, probs, ent, idx2, wtop,
                                    out + (size_t)S_ * H_, basep,
                                    sched_e, sched_c, sched_r,
                                    s2e, s2c, s2r, nsp, tokl, assw);
  k_gather<<<NPAD, 256, 0, stream>>>(x, tokl, basep, Ag);
  k_gemm1c<<<GRID1C, 256, 0, stream>>>(Ag, Tin, b_in, sched_e, sched_c, sched_r,
                                       basep, counts, nsp, actp, W_out, Tout);
  k_gemm2<<<GRID2, 256, 0, stream>>>(actp, Tout, b_out, s2e, s2c, s2r,
                                     basep, counts, nsp, tokl, assw, out);
}